// Round 10
// baseline (210.305 us; speedup 1.0000x reference)
//
#include <hip/hip_runtime.h>
#include <hip/hip_bf16.h>

typedef __hip_bfloat16 bf16;
typedef __bf16 bfx8 __attribute__((ext_vector_type(8)));
typedef __bf16 bfx4 __attribute__((ext_vector_type(4)));
typedef float f32x4 __attribute__((ext_vector_type(4)));

typedef __attribute__((address_space(3))) void lds_void_t;
typedef const __attribute__((address_space(1))) void gbl_void_t;

// ---------------------------------------------------------------------------
// Fused prep (float4 reads, 8B writes, single sync):
// HT[e][n] = bf16(H[n][e]); Hb[n][e] = bf16(H[n][e]); de/dvr accumulated.
__global__ void prep_kernel(const float* __restrict__ H, const float* __restrict__ w,
                            bf16* __restrict__ HT, bf16* __restrict__ Hb,
                            float* __restrict__ de, float* __restrict__ dvr, int N, int E) {
    __shared__ __align__(8) __bf16 tile[64][68];
    int eb = blockIdx.x * 64, nb = blockIdx.y * 64;
    int tid = threadIdx.x;
    int lane = tid & 63, g = tid >> 6;
    int cq = (lane & 15) * 4;
    int rbase = g + ((lane >> 4) << 2);

#pragma unroll
    for (int m = 0; m < 4; m++) {
        int r = rbase + (m << 4);
        f32x4 v = *(const f32x4*)&H[(size_t)(nb + r) * E + eb + cq];
        bfx4 b4;
#pragma unroll
        for (int t = 0; t < 4; t++) b4[t] = (__bf16)v[t];
        *(bfx4*)&tile[r][cq] = b4;
        if (Hb) *(bfx4*)&Hb[(size_t)(nb + r) * E + eb + cq] = b4;
    }
    __syncthreads();

    int c = lane;
    if (g == 0) {
        float s = 0.f;
#pragma unroll 8
        for (int rr = 0; rr < 64; rr++) s += (float)tile[rr][c];
        atomicAdd(&de[eb + c], s);
    } else if (g == 1) {
        float s = 0.f;
#pragma unroll 8
        for (int cc = 0; cc < 64; cc++) s += (float)tile[c][cc] * w[eb + cc];
        atomicAdd(&dvr[nb + c], s);
    }
#pragma unroll
    for (int k = 0; k < 16; k++) {
        int r = g + (k << 2);
        HT[(size_t)(eb + r) * N + nb + c] = (bf16)tile[c][r];
    }
}

// ---------------------------------------------------------------------------
// K3: xs_t[z*256+o][n] = (sum_d W[o][d]*x[z][n][d] + bias[o]) * rsqrt(dvr[n]+eps)
__global__ __launch_bounds__(256) void gemm_k3(
    const float* __restrict__ W, const float* __restrict__ x,
    const float* __restrict__ bias, const float* __restrict__ dvr,
    bf16* __restrict__ xs_t) {
    __shared__ __align__(16) bf16 As[256 * 40];
    __shared__ __align__(16) bf16 Bs[64 * 40];

    const int bx = blockIdx.x, z = blockIdx.y;
    const int tid = threadIdx.x;
    const int wave = tid >> 6, lane = tid & 63;
    const int wr = wave * 64;
    const int lcol = lane & 15, quad = lane >> 4;
    const float* xp = x + (size_t)z * 1048576 + (size_t)bx * 64 * 256;

    f32x4 acc[4][4];
#pragma unroll
    for (int i = 0; i < 4; i++)
#pragma unroll
        for (int j = 0; j < 4; j++) acc[i][j] = (f32x4){0.f, 0.f, 0.f, 0.f};

    for (int k0 = 0; k0 < 256; k0 += 32) {
#pragma unroll
        for (int c = 0; c < 4; c++) {
            int ch = tid + c * 256;
            int r = ch >> 2, kc = (ch & 3) << 3;
            f32x4 p0 = *(const f32x4*)&W[(size_t)r * 256 + k0 + kc];
            f32x4 p1 = *(const f32x4*)&W[(size_t)r * 256 + k0 + kc + 4];
            bfx8 va;
#pragma unroll
            for (int t = 0; t < 4; t++) { va[t] = (__bf16)p0[t]; va[4 + t] = (__bf16)p1[t]; }
            *(bfx8*)&As[r * 40 + kc] = va;
        }
        {
            int r = tid >> 2, kc = (tid & 3) << 3;
            f32x4 q0 = *(const f32x4*)&xp[(size_t)r * 256 + k0 + kc];
            f32x4 q1 = *(const f32x4*)&xp[(size_t)r * 256 + k0 + kc + 4];
            bfx8 vb;
#pragma unroll
            for (int t = 0; t < 4; t++) { vb[t] = (__bf16)q0[t]; vb[4 + t] = (__bf16)q1[t]; }
            *(bfx8*)&Bs[r * 40 + kc] = vb;
        }
        __syncthreads();

        bfx8 af[4], bfr[4];
#pragma unroll
        for (int i = 0; i < 4; i++)
            af[i] = *(const bfx8*)&As[(wr + i * 16 + lcol) * 40 + quad * 8];
#pragma unroll
        for (int j = 0; j < 4; j++)
            bfr[j] = *(const bfx8*)&Bs[(j * 16 + lcol) * 40 + quad * 8];
#pragma unroll
        for (int i = 0; i < 4; i++)
#pragma unroll
            for (int j = 0; j < 4; j++)
                acc[i][j] = __builtin_amdgcn_mfma_f32_16x16x32_bf16(af[i], bfr[j], acc[i][j], 0, 0, 0);
        __syncthreads();
    }

#pragma unroll
    for (int j = 0; j < 4; j++) {
        int n = bx * 64 + j * 16 + lcol;
        float dn = rsqrtf(dvr[n] + 1e-8f);
#pragma unroll
        for (int i = 0; i < 4; i++) {
#pragma unroll
            for (int r = 0; r < 4; r++) {
                int o = wr + i * 16 + quad * 4 + r;
                float v = (acc[i][j][r] + bias[o]) * dn;
                xs_t[(size_t)(z * 256 + o) * 4096 + n] = __float2bfloat16(v);
            }
        }
    }
}

// ---------------------------------------------------------------------------
// 256x256 8-phase GEMM — FALLBACK-ONLY (small-ws K5 path).
#define STG_A(cb, h, u) do { \
    __builtin_amdgcn_global_load_lds((gbl_void_t*)(ga##h##0 + (size_t)(u) * 64), \
        (lds_void_t*)&SM[(cb) * 16384 + (h) * 8192 + dOff], 16, 0, 0); \
    __builtin_amdgcn_global_load_lds((gbl_void_t*)(ga##h##1 + (size_t)(u) * 64), \
        (lds_void_t*)&SM[(cb) * 16384 + (h) * 8192 + 4096 + dOff], 16, 0, 0); \
} while (0)

#define STG_B(cb, h, u) do { \
    __builtin_amdgcn_global_load_lds((gbl_void_t*)(gb##h##0 + (size_t)(u) * 64), \
        (lds_void_t*)&SM[32768 + (cb) * 16384 + (h) * 8192 + dOff], 16, 0, 0); \
    __builtin_amdgcn_global_load_lds((gbl_void_t*)(gb##h##1 + (size_t)(u) * 64), \
        (lds_void_t*)&SM[32768 + (cb) * 16384 + (h) * 8192 + 4096 + dOff], 16, 0, 0); \
} while (0)

#define LDA_(cb, qi, i, kk) \
    (*(const bfx8*)&SM[(cb) * 16384 + aBase + ((qi) * 64 + (i) * 16) * 64 + ra##kk])
#define LDB_(cb, j, kk) \
    (*(const bfx8*)&SM[32768 + (cb) * 16384 + bjb[j] + ra##kk])

#define PH_MFMA(I0, J0) do { \
    __builtin_amdgcn_s_setprio(1); \
    _Pragma("unroll") \
    for (int i_ = 0; i_ < 4; i_++) { \
        _Pragma("unroll") \
        for (int jj_ = 0; jj_ < 2; jj_++) { \
            acc[(I0) + i_][(J0) + jj_] = __builtin_amdgcn_mfma_f32_16x16x32_bf16( \
                af[i_][0], bf[(J0) + jj_][0], acc[(I0) + i_][(J0) + jj_], 0, 0, 0); \
            acc[(I0) + i_][(J0) + jj_] = __builtin_amdgcn_mfma_f32_16x16x32_bf16( \
                af[i_][1], bf[(J0) + jj_][1], acc[(I0) + i_][(J0) + jj_], 0, 0, 0); \
        } \
    } \
    __builtin_amdgcn_s_setprio(0); \
} while (0)

#define CFENCE asm volatile("" ::: "memory")

#define KTILE(cb, uA, uB) do { \
    _Pragma("unroll") \
    for (int i_ = 0; i_ < 4; i_++) { af[i_][0] = LDA_(cb, 0, i_, 0); af[i_][1] = LDA_(cb, 0, i_, 1); } \
    _Pragma("unroll") \
    for (int j_ = 0; j_ < 2; j_++) { bf[j_][0] = LDB_(cb, j_, 0); bf[j_][1] = LDB_(cb, j_, 1); } \
    STG_A((cb) ^ 1, 0, uA); \
    __builtin_amdgcn_s_barrier(); \
    PH_MFMA(0, 0); \
    CFENCE; \
    _Pragma("unroll") \
    for (int j_ = 0; j_ < 2; j_++) { bf[2 + j_][0] = LDB_(cb, 2 + j_, 0); bf[2 + j_][1] = LDB_(cb, 2 + j_, 1); } \
    STG_A((cb) ^ 1, 1, uA); \
    __builtin_amdgcn_s_barrier(); \
    PH_MFMA(0, 2); \
    __builtin_amdgcn_s_barrier(); \
    _Pragma("unroll") \
    for (int i_ = 0; i_ < 4; i_++) { af[i_][0] = LDA_(cb, 1, i_, 0); af[i_][1] = LDA_(cb, 1, i_, 1); } \
    STG_B(cb, 0, uB); \
    __builtin_amdgcn_s_barrier(); \
    PH_MFMA(4, 2); \
    CFENCE; \
    STG_B(cb, 1, uB); \
    __builtin_amdgcn_s_barrier(); \
    PH_MFMA(4, 0); \
    asm volatile("s_waitcnt vmcnt(4)" ::: "memory"); \
    __builtin_amdgcn_s_barrier(); \
} while (0)

__global__ __launch_bounds__(512, 2) void gemm8ph(
    const bf16* __restrict__ A, const bf16* __restrict__ Bt, int Kst, int kLen,
    bf16* __restrict__ S0, bf16* __restrict__ S1, bf16* __restrict__ S2, bf16* __restrict__ S3,
    int ldc) {
    __shared__ __align__(16) bf16 SM[65536];

    const int nx = gridDim.x, ny = gridDim.y;
    const int nwg = nx * ny * gridDim.z;
    const int lin = (blockIdx.z * ny + blockIdx.y) * nx + blockIdx.x;
    const int cpx = nwg >> 3;
    const int swz = (lin & 7) * cpx + (lin >> 3);
    const int bx = swz % nx;
    const int t1 = swz / nx;
    const int by = t1 % ny;
    const int bz = t1 / ny;
    bf16* Cs = (bz == 0) ? S0 : (bz == 1) ? S1 : (bz == 2) ? S2 : S3;
    const int kBase = bz * kLen;
    const int NT = kLen >> 6;

    const int tid = threadIdx.x;
    const int lane = tid & 63, wave = tid >> 6;
    const int lcol = lane & 15, quad = lane >> 4;
    const int wr = (wave >> 2) * 128, wc = (wave & 3) * 64;
    const int aBase = (wave >> 2) * 8192;
    const int xr = lcol & 7;

    const int rowBase = by * 256, colBase = bx * 256;

    const int ra0 = lcol * 64 + ((quad ^ xr) << 3);
    const int ra1 = lcol * 64 + (((4 + quad) ^ xr) << 3);
    int bjb[4];
#pragma unroll
    for (int j = 0; j < 4; j++) {
        int rg = wc + j * 16;
        bjb[j] = ((rg >> 7) * 8192) + ((rg & 127) * 64);
    }

    const int srow = tid >> 3, slot = tid & 7;
    const int r0 = srow, r1 = srow + 64;
    const int sx0 = (slot ^ (r0 & 7)) << 3;
    const int sx1 = (slot ^ (r1 & 7)) << 3;
    const bf16* ga00 = A + (size_t)(rowBase + r0) * Kst + kBase + sx0;
    const bf16* ga01 = A + (size_t)(rowBase + r1) * Kst + kBase + sx1;
    const bf16* ga10 = A + (size_t)(rowBase + 128 + r0) * Kst + kBase + sx0;
    const bf16* ga11 = A + (size_t)(rowBase + 128 + r1) * Kst + kBase + sx1;
    const bf16* gb00 = Bt + (size_t)(colBase + r0) * Kst + kBase + sx0;
    const bf16* gb01 = Bt + (size_t)(colBase + r1) * Kst + kBase + sx1;
    const bf16* gb10 = Bt + (size_t)(colBase + 128 + r0) * Kst + kBase + sx0;
    const bf16* gb11 = Bt + (size_t)(colBase + 128 + r1) * Kst + kBase + sx1;
    const int dOff = tid * 8;

    f32x4 acc[8][4];
#pragma unroll
    for (int i = 0; i < 8; i++)
#pragma unroll
        for (int j = 0; j < 4; j++) acc[i][j] = (f32x4){0.f, 0.f, 0.f, 0.f};
    bfx8 af[4][2], bf[4][2];

    STG_A(0, 0, 0); STG_A(0, 1, 0); STG_B(0, 0, 0); STG_B(0, 1, 0);
    STG_B(1, 0, 1); STG_B(1, 1, 1);
    asm volatile("s_waitcnt vmcnt(4)" ::: "memory");
    __builtin_amdgcn_s_barrier();

    const int nPairs = NT >> 1;
    for (int it = 0; it < nPairs; ++it) {
        int u1 = 2 * it + 1;
        int u2 = 2 * it + 2; if (u2 > NT - 1) u2 = NT - 1;
        int u3 = 2 * it + 3; if (u3 > NT - 1) u3 = NT - 1;
        KTILE(0, u1, u2);
        KTILE(1, u2, u3);
    }

#pragma unroll
    for (int i = 0; i < 8; i++) {
#pragma unroll
        for (int j = 0; j < 4; j++) {
#pragma unroll
            for (int r = 0; r < 4; r++) {
                int grow = rowBase + wr + i * 16 + quad * 4 + r;
                int gcol = colBase + wc + j * 16 + lcol;
                Cs[(size_t)grow * ldc + gcol] = __float2bfloat16(acc[i][j][r]);
            }
        }
    }
}

// ---------------------------------------------------------------------------
// Shared pieces for the 256x128 2-phase kernels (R8-verified schedule).
#define STG5_A(cb, h, u) do { \
    __builtin_amdgcn_global_load_lds((gbl_void_t*)(ga##h##0 + (size_t)(u) * 64), \
        (lds_void_t*)&SM[(cb) * 16384 + (h) * 8192 + dOff], 16, 0, 0); \
    __builtin_amdgcn_global_load_lds((gbl_void_t*)(ga##h##1 + (size_t)(u) * 64), \
        (lds_void_t*)&SM[(cb) * 16384 + (h) * 8192 + 4096 + dOff], 16, 0, 0); \
} while (0)

#define STG5_B(cb, u) do { \
    __builtin_amdgcn_global_load_lds((gbl_void_t*)(gb0 + (size_t)(u) * 64), \
        (lds_void_t*)&SM[32768 + (cb) * 8192 + dOff], 16, 0, 0); \
    __builtin_amdgcn_global_load_lds((gbl_void_t*)(gb1 + (size_t)(u) * 64), \
        (lds_void_t*)&SM[32768 + (cb) * 8192 + 4096 + dOff], 16, 0, 0); \
} while (0)

#define LDA5(cb, i, kk) \
    (*(const bfx8*)&SM[(cb) * 16384 + (wr + (i) * 16) * 64 + ra##kk])
#define LDB5(cb, j, kk) \
    (*(const bfx8*)&SM[32768 + (cb) * 8192 + (wc + (j) * 16) * 64 + ra##kk])

#define PH5_MFMA(J0) do { \
    __builtin_amdgcn_s_setprio(1); \
    _Pragma("unroll") \
    for (int i_ = 0; i_ < 4; i_++) { \
        _Pragma("unroll") \
        for (int jj_ = 0; jj_ < 2; jj_++) { \
            acc[i_][(J0) + jj_] = __builtin_amdgcn_mfma_f32_16x16x32_bf16( \
                af[i_][0], bf[(J0) + jj_][0], acc[i_][(J0) + jj_], 0, 0, 0); \
            acc[i_][(J0) + jj_] = __builtin_amdgcn_mfma_f32_16x16x32_bf16( \
                af[i_][1], bf[(J0) + jj_][1], acc[i_][(J0) + jj_], 0, 0, 0); \
        } \
    } \
    __builtin_amdgcn_s_setprio(0); \
} while (0)

#define KTILE5(cb, uA, uB) do { \
    _Pragma("unroll") \
    for (int i_ = 0; i_ < 4; i_++) { af[i_][0] = LDA5(cb, i_, 0); af[i_][1] = LDA5(cb, i_, 1); } \
    _Pragma("unroll") \
    for (int j_ = 0; j_ < 4; j_++) { bf[j_][0] = LDB5(cb, j_, 0); bf[j_][1] = LDB5(cb, j_, 1); } \
    STG5_A((cb) ^ 1, 0, uA); \
    STG5_A((cb) ^ 1, 1, uA); \
    __builtin_amdgcn_s_barrier(); \
    PH5_MFMA(0); \
    __builtin_amdgcn_s_barrier(); \
    STG5_B(cb, uB); \
    PH5_MFMA(2); \
    asm volatile("s_waitcnt vmcnt(2)" ::: "memory"); \
    __builtin_amdgcn_s_barrier(); \
} while (0)

// K4 (MODE 0): A=xs_t Kst=4096, B=HT; split-K z in {0,1}; bf16 slices.
template <int MODE>
__global__ __launch_bounds__(512, 2) void gemm_tk(
    const bf16* __restrict__ A, const bf16* __restrict__ Bt, int Kst, int NT,
    bf16* __restrict__ Sout, int ldc,
    const float* __restrict__ dvr, float* __restrict__ outF) {
    __shared__ __align__(16) bf16 SM[49152];  // 96 KiB

    const int nx = gridDim.x, ny = gridDim.y;
    const int nwg = nx * ny * gridDim.z;
    const int lin = (blockIdx.z * ny + blockIdx.y) * nx + blockIdx.x;
    const int cpx = nwg >> 3;
    const int swz = (lin & 7) * cpx + (lin >> 3);
    const int bx = swz % nx;
    const int t1 = swz / nx;
    const int by = t1 % ny;
    const int bz = t1 / ny;
    const int kBase = bz * (NT << 6);

    const int tid = threadIdx.x;
    const int lane = tid & 63, wave = tid >> 6;
    const int lcol = lane & 15, quad = lane >> 4;
    const int wr = (wave >> 1) * 64;
    const int wc = (wave & 1) * 64;
    const int xr = lcol & 7;

    const int rowBase = by * 256, colBase = bx * 128;

    const int ra0 = lcol * 64 + ((quad ^ xr) << 3);
    const int ra1 = lcol * 64 + (((4 + quad) ^ xr) << 3);

    const int srow = tid >> 3, slot = tid & 7;
    const int r0 = srow, r1 = srow + 64;
    const int sx0 = (slot ^ (r0 & 7)) << 3;
    const int sx1 = (slot ^ (r1 & 7)) << 3;
    const bf16* ga00 = A + (size_t)(rowBase + r0) * Kst + kBase + sx0;
    const bf16* ga01 = A + (size_t)(rowBase + r1) * Kst + kBase + sx1;
    const bf16* ga10 = A + (size_t)(rowBase + 128 + r0) * Kst + kBase + sx0;
    const bf16* ga11 = A + (size_t)(rowBase + 128 + r1) * Kst + kBase + sx1;
    const bf16* gb0  = Bt + (size_t)(colBase + r0) * Kst + kBase + sx0;
    const bf16* gb1  = Bt + (size_t)(colBase + r1) * Kst + kBase + sx1;
    const int dOff = tid * 8;

    f32x4 acc[4][4];
#pragma unroll
    for (int i = 0; i < 4; i++)
#pragma unroll
        for (int j = 0; j < 4; j++) acc[i][j] = (f32x4){0.f, 0.f, 0.f, 0.f};
    bfx8 af[4][2], bf[4][2];

    STG5_A(0, 0, 0); STG5_A(0, 1, 0); STG5_B(0, 0);
    STG5_B(1, 1);
    asm volatile("s_waitcnt vmcnt(2)" ::: "memory");
    __builtin_amdgcn_s_barrier();

    for (int it = 0; it < NT / 2; ++it) {
        int u0 = 2 * it, u1 = 2 * it + 1;
        int a0 = u0 + 1;
        int b0 = u0 + 2; if (b0 > NT - 1) b0 = NT - 1;
        int a1 = u1 + 1; if (a1 > NT - 1) a1 = NT - 1;
        int b1 = u1 + 2; if (b1 > NT - 1) b1 = NT - 1;
        KTILE5(0, a0, b0);
        KTILE5(1, a1, b1);
    }

    if (MODE == 0) {
        bf16* Ps = Sout + (size_t)bz * 4194304;
#pragma unroll
        for (int i = 0; i < 4; i++) {
#pragma unroll
            for (int j = 0; j < 4; j++) {
#pragma unroll
                for (int r = 0; r < 4; r++) {
                    int grow = rowBase + wr + i * 16 + quad * 4 + r;
                    int gcol = colBase + wc + j * 16 + lcol;
                    Ps[(size_t)grow * ldc + gcol] = __float2bfloat16(acc[i][j][r]);
                }
            }
        }
    } else {
#pragma unroll
        for (int i = 0; i < 4; i++) {
#pragma unroll
            for (int r = 0; r < 4; r++) {
                int grow = rowBase + wr + i * 16 + quad * 4 + r;
                float dn = rsqrtf(dvr[grow] + 1e-8f);
#pragma unroll
                for (int j = 0; j < 4; j++) {
                    int gcol = colBase + wc + j * 16 + lcol;
                    outF[(size_t)(gcol >> 8) * 1048576 + (size_t)grow * 256 + (gcol & 255)] =
                        acc[i][j][r] * dn;
                }
            }
        }
    }
}

// ---------------------------------------------------------------------------
// K5-FUSED (R10): 256(n)x128(c), full K=2048; B = (s0+s1)*wsc built on the
// fly (reg-staged). Replaces combine2 + K5. Numerics identical to
// combine2 path (same values, same single bf16 rounding at ds_write).
// Per tile u (buffer cb=u&1):
//  P1: ds_read af/bf from cb; STG5_A(u+1)->cb^1; issue 4 B global_loads(u+1)
//      (s0/s1, rows r0/r1, L2-hot from K4); bar; MFMA j01; bar.
//  P2: vmcnt(0) (loads issued ~1 phase ago, L2 latency covered); read wscL
//      (LDS, filled in prologue); combine -> 2x bfx8; ds_write -> cb^1 B
//      (idle region: tile u reads cb; all waves in P2 between barriers);
//      MFMA j23 (regs from P1); lgkmcnt(0) (ds_writes visible cross-wave);
//      bar.
#define KT5F(cb, uN) do { \
    _Pragma("unroll") \
    for (int i_ = 0; i_ < 4; i_++) { af[i_][0] = LDA5(cb, i_, 0); af[i_][1] = LDA5(cb, i_, 1); } \
    _Pragma("unroll") \
    for (int j_ = 0; j_ < 4; j_++) { bf[j_][0] = LDB5(cb, j_, 0); bf[j_][1] = LDB5(cb, j_, 1); } \
    STG5_A((cb) ^ 1, 0, uN); \
    STG5_A((cb) ^ 1, 1, uN); \
    br00 = *(const bfx8*)&S0b[(size_t)(uN) * 64]; \
    br01 = *(const bfx8*)&S1b[(size_t)(uN) * 64]; \
    br10 = *(const bfx8*)&S0c[(size_t)(uN) * 64]; \
    br11 = *(const bfx8*)&S1c[(size_t)(uN) * 64]; \
    __builtin_amdgcn_s_barrier(); \
    PH5_MFMA(0); \
    __builtin_amdgcn_s_barrier(); \
    asm volatile("s_waitcnt vmcnt(0)" ::: "memory"); \
    { \
        f32x4 w0a = *(const f32x4*)&wscL[(uN) * 64 + sx0]; \
        f32x4 w0b = *(const f32x4*)&wscL[(uN) * 64 + sx0 + 4]; \
        f32x4 w1a = *(const f32x4*)&wscL[(uN) * 64 + sx1]; \
        f32x4 w1b = *(const f32x4*)&wscL[(uN) * 64 + sx1 + 4]; \
        bfx8 o0, o1; \
        _Pragma("unroll") \
        for (int t_ = 0; t_ < 4; t_++) { \
            o0[t_]     = (__bf16)(((float)br00[t_]     + (float)br01[t_])     * w0a[t_]); \
            o0[4 + t_] = (__bf16)(((float)br00[4 + t_] + (float)br01[4 + t_]) * w0b[t_]); \
            o1[t_]     = (__bf16)(((float)br10[t_]     + (float)br11[t_])     * w1a[t_]); \
            o1[4 + t_] = (__bf16)(((float)br10[4 + t_] + (float)br11[4 + t_]) * w1b[t_]); \
        } \
        *(bfx8*)&SM[32768 + ((cb) ^ 1) * 8192 + dOff] = o0; \
        *(bfx8*)&SM[32768 + ((cb) ^ 1) * 8192 + 4096 + dOff] = o1; \
    } \
    PH5_MFMA(2); \
    asm volatile("s_waitcnt lgkmcnt(0)" ::: "memory"); \
    __builtin_amdgcn_s_barrier(); \
} while (0)

__global__ __launch_bounds__(512, 2) void gemm_k5f(
    const bf16* __restrict__ A, const bf16* __restrict__ S0v, const bf16* __restrict__ S1v,
    const float* __restrict__ ew, const float* __restrict__ de,
    const float* __restrict__ dvr, float* __restrict__ outF) {
    __shared__ __align__(16) bf16 SM[49152];   // A 2x32KB | B 2x16KB
    __shared__ __align__(16) float wscL[2048]; // +8KB (104KB total, 1 blk/CU)
    const int Kst = 2048, NT = 32;

    const int nx = gridDim.x, ny = gridDim.y;
    const int nwg = nx * ny;
    const int lin = blockIdx.y * nx + blockIdx.x;
    const int cpx = nwg >> 3;
    const int swz = (lin & 7) * cpx + (lin >> 3);
    const int bx = swz % nx;
    const int by = swz / nx;

    const int tid = threadIdx.x;
    const int lane = tid & 63, wave = tid >> 6;
    const int lcol = lane & 15, quad = lane >> 4;
    const int wr = (wave >> 1) * 64;
    const int wc = (wave & 1) * 64;
    const int xr = lcol & 7;

    const int rowBase = by * 256, colBase = bx * 128;

    const int ra0 = lcol * 64 + ((quad ^ xr) << 3);
    const int ra1 = lcol * 64 + (((4 + quad) ^ xr) << 3);

    const int srow = tid >> 3, slot = tid & 7;
    const int r0 = srow, r1 = srow + 64;
    const int sx0 = (slot ^ (r0 & 7)) << 3;
    const int sx1 = (slot ^ (r1 & 7)) << 3;
    const bf16* ga00 = A + (size_t)(rowBase + r0) * Kst + sx0;
    const bf16* ga01 = A + (size_t)(rowBase + r1) * Kst + sx1;
    const bf16* ga10 = A + (size_t)(rowBase + 128 + r0) * Kst + sx0;
    const bf16* ga11 = A + (size_t)(rowBase + 128 + r1) * Kst + sx1;
    const bf16* S0b = S0v + (size_t)(colBase + r0) * 2048 + sx0;
    const bf16* S1b = S1v + (size_t)(colBase + r0) * 2048 + sx0;
    const bf16* S0c = S0v + (size_t)(colBase + r1) * 2048 + sx1;
    const bf16* S1c = S1v + (size_t)(colBase + r1) * 2048 + sx1;
    const int dOff = tid * 8;

    f32x4 acc[4][4];
#pragma unroll
    for (int i = 0; i < 4; i++)
#pragma unroll
        for (int j = 0; j < 4; j++) acc[i][j] = (f32x4){0.f, 0.f, 0.f, 0.f};
    bfx8 af[4][2], bf[4][2];
    bfx8 br00, br01, br10, br11;

    // prologue: A(0) via gload_lds; B(0) regs; wscL fill; build B(0)->buf0
    STG5_A(0, 0, 0); STG5_A(0, 1, 0);
    br00 = *(const bfx8*)&S0b[0];
    br01 = *(const bfx8*)&S1b[0];
    br10 = *(const bfx8*)&S0c[0];
    br11 = *(const bfx8*)&S1c[0];
    {
        int wi = tid * 4;
#pragma unroll
        for (int t = 0; t < 4; t++) wscL[wi + t] = ew[wi + t] / (de[wi + t] + 1e-8f);
    }
    __syncthreads();  // drains vm (A0 + B0 regs) + lgkm + barrier
    {
        f32x4 w0a = *(const f32x4*)&wscL[sx0];
        f32x4 w0b = *(const f32x4*)&wscL[sx0 + 4];
        f32x4 w1a = *(const f32x4*)&wscL[sx1];
        f32x4 w1b = *(const f32x4*)&wscL[sx1 + 4];
        bfx8 o0, o1;
#pragma unroll
        for (int t = 0; t < 4; t++) {
            o0[t]     = (__bf16)(((float)br00[t]     + (float)br01[t])     * w0a[t]);
            o0[4 + t] = (__bf16)(((float)br00[4 + t] + (float)br01[4 + t]) * w0b[t]);
            o1[t]     = (__bf16)(((float)br10[t]     + (float)br11[t])     * w1a[t]);
            o1[4 + t] = (__bf16)(((float)br10[4 + t] + (float)br11[4 + t]) * w1b[t]);
        }
        *(bfx8*)&SM[32768 + dOff] = o0;
        *(bfx8*)&SM[32768 + 4096 + dOff] = o1;
    }
    __syncthreads();  // B(0) visible to all waves

    for (int it = 0; it < NT / 2; ++it) {
        int uA = 2 * it + 1;                               // <= NT-1 always
        int uB = 2 * it + 2; if (uB > NT - 1) uB = NT - 1; // tail restage
        KT5F(0, uA);
        KT5F(1, uB);
    }

    // epilogue: final f32 out[b][n][o], n=grow, b=gcol>>8, o=gcol&255
#pragma unroll
    for (int i = 0; i < 4; i++) {
#pragma unroll
        for (int r = 0; r < 4; r++) {
            int grow = rowBase + wr + i * 16 + quad * 4 + r;
            float dn = rsqrtf(dvr[grow] + 1e-8f);
#pragma unroll
            for (int j = 0; j < 4; j++) {
                int gcol = colBase + wc + j * 16 + lcol;
                outF[(size_t)(gcol >> 8) * 1048576 + (size_t)grow * 256 + (gcol & 255)] =
                    acc[i][j][r] * dn;
            }
        }
    }
}

// ---------------------------------------------------------------------------
// t_t[c][e] = bf16((s0+s1) * w[e]/(de[e]+eps))  — fallback only
__global__ void combine2_kernel(const bf16* __restrict__ s0, const bf16* __restrict__ s1,
                                const float* __restrict__ w, const float* __restrict__ de,
                                bf16* __restrict__ tt) {
    size_t i = ((size_t)blockIdx.x * 256 + threadIdx.x) * 8;
    int e = (int)(i & 2047);
    bfx8 a = *(const bfx8*)&s0[i];
    bfx8 b = *(const bfx8*)&s1[i];
    bfx8 v;
#pragma unroll
    for (int t = 0; t < 8; t++) {
        float ws = w[e + t] / (de[e + t] + 1e-8f);
        v[t] = (__bf16)(((float)a[t] + (float)b[t]) * ws);
    }
    *(bfx8*)&tt[i] = v;
}

// fallback-only kernels (small-ws path)
__global__ void transpose_kernel(const bf16* __restrict__ src, bf16* __restrict__ dst,
                                 int R, int C) {
    __shared__ __bf16 t[64][68];
    int cb = blockIdx.x * 64, rb = blockIdx.y * 64;
    int tid = threadIdx.x;
    int lc = tid & 7, lr = tid >> 3;
#pragma unroll
    for (int p = 0; p < 2; p++) {
        int r = lr + p * 32;
        bfx8 v = *(const bfx8*)&src[(size_t)(rb + r) * C + cb + lc * 8];
#pragma unroll
        for (int q = 0; q < 8; q++) t[r][lc * 8 + q] = v[q];
    }
    __syncthreads();
#pragma unroll
    for (int p = 0; p < 2; p++) {
        int c = lr + p * 32;
        bfx8 v;
#pragma unroll
        for (int q = 0; q < 8; q++) v[q] = t[lc * 8 + q][c];
        *(bfx8*)&dst[(size_t)(cb + c) * R + rb + lc * 8] = v;
    }
}

__global__ void combine_out_kernel(const bf16* __restrict__ sA, const bf16* __restrict__ sB,
                                   const float* __restrict__ dvr, float* __restrict__ out) {
    size_t t8 = ((size_t)blockIdx.x * 256 + threadIdx.x) * 8;
    int n = (int)((t8 >> 8) & 4095);
    size_t si = (size_t)n * 2048 + (size_t)(t8 >> 20) * 256 + (t8 & 255);
    bfx8 a = *(const bfx8*)&sA[si];
    bfx8 bb = *(const bfx8*)&sB[si];
    float d = rsqrtf(dvr[n] + 1e-8f);
    f32x4 v0, v1;
#pragma unroll
    for (int t = 0; t < 4; t++) {
        v0[t] = d * ((float)a[t] + (float)bb[t]);
        v1[t] = d * ((float)a[4 + t] + (float)bb[4 + t]);
    }
    *(f32x4*)&out[t8] = v0;
    *(f32x4*)&out[t8 + 4] = v1;
}

// ---------------------------------------------------------------------------
extern "C" void kernel_launch(void* const* d_in, const int* in_sizes, int n_in,
                              void* d_out, int out_size, void* d_ws, size_t ws_size,
                              hipStream_t stream) {
    const float* x    = (const float*)d_in[0];
    const float* ew   = (const float*)d_in[1];
    const float* H    = (const float*)d_in[2];
    const float* W    = (const float*)d_in[3];
    const float* bias = (const float*)d_in[4];

    const int N = 4096, E = 2048;

    char* ws = (char*)d_ws;
    float* de   = (float*)(ws);
    float* dvr  = (float*)(ws + 8192);
    bf16*  HT   = (bf16*)(ws + 65536);                 // [E][N] 16 MB
    bf16*  xs_t = (bf16*)(ws + 65536 + 16777216);      // [2048][4096] 16 MB
    bf16*  t_t  = (bf16*)(ws + 65536 + 33554432);      // [2048][2048]  8 MB (fallback)
    bf16*  wsHb = (bf16*)(ws + 65536 + 41943040);      // [N][E] 16 MB
    const bool bigws = ws_size >= 58785792ull + 4096ull;

    bf16* s0 = (bf16*)d_out;                           // K4 slice 0 (8 MB)
    bf16* s1 = s0 + 4194304;                           // K4 slice 1 (8 MB)

    (void)hipMemsetAsync(ws, 0, 24576, stream);  // de + dvr

    prep_kernel<<<dim3(E / 64, N / 64), 256, 0, stream>>>(
        H, ew, HT, bigws ? wsHb : nullptr, de, dvr, N, E);

    gemm_k3<<<dim3(64, 8), 256, 0, stream>>>(W, x, bias, dvr, xs_t);

    // K4 split-K=2, 256(c)x128(e) tiles, kLen=2048 (NT=32): slices in d_out
    gemm_tk<0><<<dim3(16, 8, 2), 512, 0, stream>>>(
        xs_t, HT, 4096, 32, s0, 2048, nullptr, nullptr);

    if (bigws) {
        // K5-fused: reads s0,s1 directly, builds B=(s0+s1)*wsc on the fly,
        // writes final f32 out (slices dead once read; out overwrites d_out)
        gemm_k5f<<<dim3(16, 16), 512, 0, stream>>>(
            wsHb, s0, s1, ew, de, dvr, (float*)d_out);
    } else {
        // fallback: combine2 -> t_t, Hb via transpose, 8-phase split-K K5
        combine2_kernel<<<dim3(2048), 256, 0, stream>>>(s0, s1, ew, de, t_t);
        bf16* HbP = (bf16*)d_out;
        transpose_kernel<<<dim3(64, 32), 256, 0, stream>>>(HT, HbP, 2048, 4096);
        bf16* k5a = HT;
        bf16* k5b = xs_t;
        gemm8ph<<<dim3(8, 16, 2), 512, 0, stream>>>(HbP, t_t, 2048, 1024, k5a, k5b, k5a, k5a, 2048);
        combine_out_kernel<<<dim3(4096), 256, 0, stream>>>(k5a, k5b, dvr, (float*)d_out);
    }
}